// Round 1
// baseline (189.258 us; speedup 1.0000x reference)
//
#include <hip/hip_runtime.h>

// PillarMaxPooling R13: drop the scatter read-filter.
// Theory: per point the 32 lanes cover exactly 2 output lines; the filter only
// saves a line-transaction when ALL 16 lanes of a line fail (~2-3% given ~6.7
// pts/pillar in random order). It COSTS a dependent 128B read + a
// load->cmp->atomic serialization every iteration. Fire-and-forget atomicMax
// is pure throughput. Also: fold (w0+w3, w1+w4, w2+w5, -CZ*w2) into registers,
// and non-temporal the single-use point streams (xyz/ptf/sidx) so L2 keeps
// pil + the atomic working set.
// Ledger (R1-R12): harness constant ~85us; scatter floor ~74us (R7, atomics
// only); moments kernel deleted in R12 (stats folded into scatter: 2 FMA/pt +
// block reduce + 64-way replicated atomicAdd). Bucket+gather-pool regressed
// (R11, 122us). Named scalars only (local arrays spill on this toolchain).

#define CMLP 32
#define BN_EPS 1e-3f
#define PSIZE 0.075f
#define XMIN -54.0f
#define YMIN -54.0f
#define CZ   -1.0f   // 0.5*(Z_MIN+Z_MAX)
#define NREP 64      // stats replicas (64 lines apart -> <=64 atomics/address)
#define SCATB 4096

// monotone float<->uint order map; u==0 unreachable from real data -> empty sentinel
__device__ __forceinline__ unsigned enc_f(float x) {
  unsigned b = __float_as_uint(x);
  return (b & 0x80000000u) ? ~b : (b | 0x80000000u);
}
__device__ __forceinline__ float dec_f(unsigned u) {
  unsigned b = (u & 0x80000000u) ? (u & 0x7fffffffu) : ~u;
  return __uint_as_float(b);
}

__global__ void __launch_bounds__(256) scatter_stats_kernel(
    const float* __restrict__ xyz, const float* __restrict__ ptf,
    const float* __restrict__ W1, const float* __restrict__ gamma,
    const int* __restrict__ pil, const int* __restrict__ sidx,
    float* __restrict__ stats_rep, unsigned* __restrict__ outenc, int N) {
  const int tid = threadIdx.x;
  const int c = tid & 31;
  // folded weights: h = x*(w0+w3) + y*(w1+w4) + z*(w2+w5)
  //                   - cx*w0 - cy*w1 - CZ*w2 + ptf . w6..w10
  const float w0 = W1[0 * CMLP + c], w1 = W1[1 * CMLP + c];
  const float w2 = W1[2 * CMLP + c];
  const float wx = w0 + W1[3 * CMLP + c];
  const float wy = w1 + W1[4 * CMLP + c];
  const float wz = w2 + W1[5 * CMLP + c];
  const float nw0 = -w0, nw1 = -w1;
  const float c0 = -CZ * w2;
  const float w6 = W1[6 * CMLP + c], w7 = W1[7 * CMLP + c];
  const float w8 = W1[8 * CMLP + c], w9 = W1[9 * CMLP + c];
  const float w10 = W1[10 * CMLP + c];
  const float sgn = (gamma[c] < 0.f) ? -1.f : 1.f;  // sign(sc)=sign(gamma)
  float s = 0.f, ss = 0.f;  // per-channel h moments (this thread's points)
  // half-wave per point; 32 lanes issue the same addresses -> HW broadcast
  const int hw0 = (blockIdx.x * 256 + tid) >> 5;
  const int nhw = (SCATB * 256) >> 5;
  int p = hw0;
  int m = (p < N) ? __builtin_nontemporal_load(&sidx[p]) : 0;
  while (p < N) {
    const int pn = p + nhw;
    const int mn = (pn < N) ? __builtin_nontemporal_load(&sidx[pn]) : 0;
    float cx = fmaf((float)pil[3 * m + 2] + 0.5f, PSIZE, XMIN);
    float cy = fmaf((float)pil[3 * m + 1] + 0.5f, PSIZE, YMIN);
    float x = __builtin_nontemporal_load(&xyz[3 * p]);
    float y = __builtin_nontemporal_load(&xyz[3 * p + 1]);
    float z = __builtin_nontemporal_load(&xyz[3 * p + 2]);
    float h = c0;
    h = fmaf(x, wx, h);
    h = fmaf(y, wy, h);
    h = fmaf(z, wz, h);
    h = fmaf(cx, nw0, h);
    h = fmaf(cy, nw1, h);
    h = fmaf(__builtin_nontemporal_load(&ptf[5 * p + 0]), w6, h);
    h = fmaf(__builtin_nontemporal_load(&ptf[5 * p + 1]), w7, h);
    h = fmaf(__builtin_nontemporal_load(&ptf[5 * p + 2]), w8, h);
    h = fmaf(__builtin_nontemporal_load(&ptf[5 * p + 3]), w9, h);
    h = fmaf(__builtin_nontemporal_load(&ptf[5 * p + 4]), w10, h);
    s += h;
    ss = fmaf(h, h, ss);
    // fire-and-forget: no read-filter, no dependent wait before the atomic
    atomicMax(&outenc[m * CMLP + c], enc_f(sgn * h));
    p = pn;
    m = mn;
  }
  // lanes L and L+32 hold the same channel -> combine, stage, block-reduce
  s += __shfl_xor(s, 32);
  ss += __shfl_xor(ss, 32);
  __shared__ float red[4][64];
  const int wave = tid >> 6, lane = tid & 63;
  if (lane < 32) {
    red[wave][lane] = s;
    red[wave][32 + lane] = ss;
  }
  __syncthreads();
  if (tid < 64) {
    float v = red[0][tid] + red[1][tid] + red[2][tid] + red[3][tid];
    // replica blockIdx&63: 64 blocks/address -> no hot-line serialization
    atomicAdd(&stats_rep[(blockIdx.x & (NREP - 1)) * 64 + tid], v);
  }
}

__global__ void finalize_kernel(const float* __restrict__ gamma,
                                const float* __restrict__ beta,
                                const float* __restrict__ stats_rep,
                                float* __restrict__ affine, float invN) {
  int c = threadIdx.x;
  if (c < CMLP) {
    float s = 0.f, ss = 0.f;
    for (int r = 0; r < NREP; r++) {
      s += stats_rep[r * 64 + c];
      ss += stats_rep[r * 64 + 32 + c];
    }
    float mean = s * invN;
    float var = ss * invN - mean * mean;          // biased, like jnp.var
    float sc = gamma[c] * rsqrtf(var + BN_EPS);
    affine[c] = sc;                               // scale
    affine[CMLP + c] = beta[c] - mean * sc;       // bias
  }
}

__global__ void __launch_bounds__(256) transform_kernel(
    unsigned* __restrict__ io, const float* __restrict__ affine, int total) {
  int i = blockIdx.x * 256 + threadIdx.x;
  if (i < total) {
    unsigned u = io[i];
    int c = i & 31;
    float v = 0.f;  // u==0 <=> empty pillar -> 0 (matches max then relu floor)
    if (u) v = fmaxf(fmaf(fabsf(affine[c]), dec_f(u), affine[CMLP + c]), 0.f);
    io[i] = __float_as_uint(v);
  }
}

extern "C" void kernel_launch(void* const* d_in, const int* in_sizes, int n_in,
                              void* d_out, int out_size, void* d_ws, size_t ws_size,
                              hipStream_t stream) {
  const float* xyz = (const float*)d_in[0];
  const float* ptf = (const float*)d_in[1];
  const float* W1 = (const float*)d_in[2];
  const float* gamma = (const float*)d_in[3];
  const float* beta = (const float*)d_in[4];
  const int* pil = (const int*)d_in[5];
  const int* sidx = (const int*)d_in[6];
  unsigned* out = (unsigned*)d_out;

  int N = in_sizes[0] / 3;

  // ws: [0, 16KB) stats replicas (64 x {s[32], ss[32]}); [16KB, +256B) affine
  float* stats_rep = (float*)d_ws;
  float* affine = (float*)((char*)d_ws + NREP * 64 * sizeof(float));

  hipMemsetAsync(stats_rep, 0, NREP * 64 * sizeof(float), stream);
  hipMemsetAsync(out, 0, (size_t)out_size * sizeof(unsigned), stream);

  scatter_stats_kernel<<<SCATB, 256, 0, stream>>>(xyz, ptf, W1, gamma, pil,
                                                  sidx, stats_rep, out, N);
  finalize_kernel<<<1, 64, 0, stream>>>(gamma, beta, stats_rep, affine,
                                        1.0f / (float)N);
  transform_kernel<<<(out_size + 255) / 256, 256, 0, stream>>>(out, affine,
                                                               out_size);
}